// Round 3
// baseline (163.676 us; speedup 1.0000x reference)
//
#include <hip/hip_runtime.h>

// qpNet: h = x @ W^T + b ; z = max(-h, -1000). x:[B,5] f32, W:[5,5], b:[5].
// B = 4194304. Memory-bound: 168 MB app traffic, floor ~27 us @ 6.3 TB/s.
//
// R2: 80 B lane stride, one-shot       -> 57 us
// R3: block LDS transpose + barrier    -> 50 us
// R5: 64 B stride + nontemporal stores -> 82 us (nt defeats L2 write-combine)
// R6: wave-private LDS transpose       -> ~50 us
// R7: R6 + register prefetch pipeline  -> 51.4 us, 2.45 TB/s HBM (30%),
//     FETCH 42 MB (x half L3-hit), WRITE 84 MB. Traffic exact; RATE is 2x
//     under the 6.3 TB/s copy ubench. Prefetch changed nothing.
// R8: copy-shaped kernel, no LDS  -> INFRA FAILURE (container died twice,
//     never measured). This is R8 resubmitted unchanged (R9).
//     Diagnosis fork: every LDS variant serializes each tile behind two full
//     LDS round trips with hard lgkmcnt(0) fences (~1400 ordered cycles/tile),
//     holding the per-wave memory duty cycle near zero; OR the memory system
//     caps at ~3.3 TB/s here. Decisive test = the structure that matches the
//     6.3 TB/s copy ubench exactly: lane loads 5 CONSECUTIVE vf4 = 20
//     contiguous floats = 4 complete rows (lcm(4,5)=20), computes 4 matvecs
//     in-lane, stores 20 contiguous floats. Zero LDS, zero lgkmcnt, only
//     vmcnt waits. 2 tiles/wave, all 10 loads issued up front (10 KB in
//     flight/wave); no LDS -> 32 waves/CU occupancy. Known cost: 80 B lane
//     stride = ~4x L2 request amplification (each 64 B line touched by 4
//     instrs, fetched once) -- L2 has ~10x headroom, shouldn't bind.
//     If this ties ~50 us, the harness memory state is the ceiling (ROOFLINE).

#define BLOCK 256
#define WAVES_PER_BLOCK 4          // BLOCK / 64
#define F4_PER_TILE 320            // 64 lanes * 5 f4 = 1280 floats = 256 rows
#define TILES_PER_WAVE 2           // 8192 waves total = 2048 blocks

typedef float vf4 __attribute__((ext_vector_type(4)));

// Compute 4 rows in place on 5 vf4 (= 20 contiguous floats = rows 0..3).
// All indices compile-time constant -> stays in VGPRs.
__device__ __forceinline__ void process4(vf4 a[5], const float w[5][5],
                                         const float bias[5]) {
    float v[20];
#pragma unroll
    for (int k = 0; k < 5; ++k)
#pragma unroll
        for (int c = 0; c < 4; ++c) v[k * 4 + c] = a[k][c];

#pragma unroll
    for (int r = 0; r < 4; ++r) {
        float t0 = bias[0], t1 = bias[1], t2 = bias[2], t3 = bias[3], t4 = bias[4];
#pragma unroll
        for (int i = 0; i < 5; ++i) {
            const float xv = v[r * 5 + i];
            t0 = fmaf(xv, w[0][i], t0);
            t1 = fmaf(xv, w[1][i], t1);
            t2 = fmaf(xv, w[2][i], t2);
            t3 = fmaf(xv, w[3][i], t3);
            t4 = fmaf(xv, w[4][i], t4);
        }
        v[r * 5 + 0] = fmaxf(-t0, -1000.0f);
        v[r * 5 + 1] = fmaxf(-t1, -1000.0f);
        v[r * 5 + 2] = fmaxf(-t2, -1000.0f);
        v[r * 5 + 3] = fmaxf(-t3, -1000.0f);
        v[r * 5 + 4] = fmaxf(-t4, -1000.0f);
    }

#pragma unroll
    for (int k = 0; k < 5; ++k)
#pragma unroll
        for (int c = 0; c < 4; ++c) a[k][c] = v[k * 4 + c];
}

__global__ __launch_bounds__(BLOCK) void qpnet_kernel(
    const float* __restrict__ x,
    const float* __restrict__ W,
    const float* __restrict__ bfc,
    float* __restrict__ out,
    int total_f4)
{
    // 5x5 weights + bias (wave-uniform addresses -> scalar-cached).
    float w[5][5];
    float bias[5];
#pragma unroll
    for (int j = 0; j < 5; ++j) {
        bias[j] = bfc[j];
#pragma unroll
        for (int i = 0; i < 5; ++i) w[j][i] = W[j * 5 + i];
    }

    const int wave = threadIdx.x >> 6;
    const int lane = threadIdx.x & 63;
    const int wave_id = blockIdx.x * WAVES_PER_BLOCK + wave;

    const vf4* __restrict__ xin  = reinterpret_cast<const vf4*>(x);
    vf4* __restrict__       zout = reinterpret_cast<vf4*>(out);

    // Lane owns 20 contiguous floats (5 consecutive f4) per tile.
    // base0 max = 5,242,875 -> fits int.
    const int base0 = wave_id * (F4_PER_TILE * TILES_PER_WAVE) + lane * 5;
    const int base1 = base0 + F4_PER_TILE;
    const bool do0 = (base0 + 5 <= total_f4);
    const bool do1 = (base1 + 5 <= total_f4);
    if (!do0) return;                              // exact division in harness

    // ---- issue ALL loads up front: 10 dwordx4 in flight per lane.
    vf4 a[5], b[5];
#pragma unroll
    for (int k = 0; k < 5; ++k) a[k] = xin[base0 + k];
    if (do1) {
#pragma unroll
        for (int k = 0; k < 5; ++k) b[k] = xin[base1 + k];
    }

    // ---- tile 0: compiler waits vmcnt(5) (b still in flight), compute, store
    process4(a, w, bias);
#pragma unroll
    for (int k = 0; k < 5; ++k) zout[base0 + k] = a[k];

    // ---- tile 1: waits vmcnt(5) again (a-stores outstanding, b loads older
    // in program order so they retire first), compute, store
    if (do1) {
        process4(b, w, bias);
#pragma unroll
        for (int k = 0; k < 5; ++k) zout[base1 + k] = b[k];
    }
}

extern "C" void kernel_launch(void* const* d_in, const int* in_sizes, int n_in,
                              void* d_out, int out_size, void* d_ws, size_t ws_size,
                              hipStream_t stream) {
    const float* x   = (const float*)d_in[0];   // [B,5]
    const float* W   = (const float*)d_in[1];   // [5,5]
    const float* bfc = (const float*)d_in[2];   // [5]
    float* out = (float*)d_out;                 // [B,5]

    int total_f4 = in_sizes[0] / 4;             // 5,242,880
    int f4_per_wave = F4_PER_TILE * TILES_PER_WAVE;                    // 640
    int n_waves  = (total_f4 + f4_per_wave - 1) / f4_per_wave;         // 8192
    int grid     = (n_waves + WAVES_PER_BLOCK - 1) / WAVES_PER_BLOCK;  // 2048

    qpnet_kernel<<<grid, BLOCK, 0, stream>>>(x, W, bfc, out, total_f4);
}

// Round 4
// 152.836 us; speedup vs baseline: 1.0709x; 1.0709x over previous
//
#include <hip/hip_runtime.h>

// qpNet: h = x @ W^T + b ; z = max(-h, -1000). x:[B,5] f32, W:[5,5], b:[5].
// B = 4194304. Memory-bound: 168 MB app traffic, floor ~27 us @ 6.3 TB/s.
//
// R2: 80 B lane stride, one-shot       -> 57 us
// R3: block LDS transpose + barrier    -> 50 us
// R5: 64 B stride + nontemporal stores -> 82 us (nt defeats L2 write-combine)
// R6: wave-private LDS transpose       -> ~50 us
// R7: R6 + "register prefetch"         -> 51.4 us. VGPR=28 (!): r[5]+v[20]
//     can't fit in 28 -> compiler SANK the prefetch loads to their use site.
//     The pipeline never existed in the emitted code.
// R9: no-LDS copy-shape, 80 B stride   -> 61 us, VGPR=28 again (b[] sunk past
//     tile-0 compute; do1-branches merged). Coalescing costs ~20%; LDS chain
//     exonerated (removing it didn't help).
// R10 (this): R7 structure + __builtin_amdgcn_sched_barrier(0) pinning the
//     next-tile loads ABOVE the dependent compute phase. The scheduler cannot
//     move memory ops across sched_barrier(0), so the prefetch must stay
//     issued while tile t's LDS/compute/store chain runs. Signature to check
//     in counters: VGPR_Count must jump to ~48-64. If VGPR jumps and time
//     drops to ~32-40 us: de-pipelining was the limiter. If VGPR jumps and
//     time stays ~50 us: per-CU read concurrency cap is real -> roofline.

#define BLOCK 256
#define WAVES_PER_BLOCK 4          // BLOCK / 64
#define F4_PER_TILE 320            // 64 lanes * 5 f4 = 1280 floats = 256 rows
#define TILES_PER_WAVE 4           // 4096 waves total = 1024 blocks

typedef float vf4 __attribute__((ext_vector_type(4)));

__global__ __launch_bounds__(BLOCK) void qpnet_kernel(
    const float* __restrict__ x,
    const float* __restrict__ W,
    const float* __restrict__ bfc,
    float* __restrict__ out,
    int total_f4)
{
    __shared__ __align__(16) float lds[BLOCK * 20];   // 20 KB: 5 KB per wave

    // 5x5 weights + bias. Uniform addresses -> compiler scalarizes (s_load).
    float w[5][5];
    float bias[5];
#pragma unroll
    for (int j = 0; j < 5; ++j) {
        bias[j] = bfc[j];
#pragma unroll
        for (int i = 0; i < 5; ++i) w[j][i] = W[j * 5 + i];
    }

    const int wave = threadIdx.x >> 6;
    const int lane = threadIdx.x & 63;
    float* __restrict__ wlds = &lds[wave * (64 * 20)];   // this wave's 1280 floats

    const int wave_id = blockIdx.x * WAVES_PER_BLOCK + wave;
    const int tb = wave_id * (F4_PER_TILE * TILES_PER_WAVE);  // f4 units; fits int
    if (tb >= total_f4) return;                               // exact division

    const vf4* __restrict__ xin  = reinterpret_cast<const vf4*>(x);
    vf4* __restrict__       zout = reinterpret_cast<vf4*>(out);

    // ---- prologue: tile 0 loads (lane-contiguous, full-line)
    vf4 r[5];
#pragma unroll
    for (int k = 0; k < 5; ++k) r[k] = xin[tb + k * 64 + lane];

#pragma unroll
    for (int t = 0; t < TILES_PER_WAVE; ++t) {
        const int cur = tb + t * F4_PER_TILE;

        // ---- stage current tile: regs -> LDS (waits vmcnt on r's loads only;
        // older stores may still be outstanding).
#pragma unroll
        for (int k = 0; k < 5; ++k)
            *reinterpret_cast<vf4*>(&wlds[(k * 64 + lane) * 4]) = r[k];

        // ---- issue NEXT tile's loads NOW, and PIN them here. sched_barrier(0)
        // forbids the scheduler from sinking these past the dependent chain
        // below — this is the fix for the R7/R9 de-pipelining (VGPR=28 proof).
        vf4 rn[5];
        if (t + 1 < TILES_PER_WAVE) {
            const int nxt = cur + F4_PER_TILE;
#pragma unroll
            for (int k = 0; k < 5; ++k) rn[k] = xin[nxt + k * 64 + lane];
        }
        __builtin_amdgcn_sched_barrier(0);

        // Intra-wave exchange: SIMD lockstep + in-order DS pipe; drain lgkm
        // and fence the compiler (no __syncthreads needed, wave-private LDS).
        asm volatile("s_waitcnt lgkmcnt(0)" ::: "memory");

        // ---- transposed read: own 20 consecutive floats = 4 complete rows
        // (word addr lane*20 + 4p: stride-20 f4 groups cover all 32 banks / 8 lanes)
        float v[20];
#pragma unroll
        for (int p = 0; p < 5; ++p)
            *reinterpret_cast<vf4*>(&v[4 * p]) =
                *reinterpret_cast<const vf4*>(&wlds[lane * 20 + 4 * p]);

        // ---- compute: 4 rows x (5x5 matvec + bias + clamp), in place
#pragma unroll
        for (int k = 0; k < 4; ++k) {
            float t0 = bias[0], t1 = bias[1], t2 = bias[2], t3 = bias[3], t4 = bias[4];
#pragma unroll
            for (int i = 0; i < 5; ++i) {
                const float xv = v[k * 5 + i];
                t0 = fmaf(xv, w[0][i], t0);
                t1 = fmaf(xv, w[1][i], t1);
                t2 = fmaf(xv, w[2][i], t2);
                t3 = fmaf(xv, w[3][i], t3);
                t4 = fmaf(xv, w[4][i], t4);
            }
            v[k * 5 + 0] = fmaxf(-t0, -1000.0f);
            v[k * 5 + 1] = fmaxf(-t1, -1000.0f);
            v[k * 5 + 2] = fmaxf(-t2, -1000.0f);
            v[k * 5 + 3] = fmaxf(-t3, -1000.0f);
            v[k * 5 + 4] = fmaxf(-t4, -1000.0f);
        }

        // ---- transposed write back to own region
#pragma unroll
        for (int p = 0; p < 5; ++p)
            *reinterpret_cast<vf4*>(&wlds[lane * 20 + 4 * p]) =
                *reinterpret_cast<const vf4*>(&v[4 * p]);
        asm volatile("s_waitcnt lgkmcnt(0)" ::: "memory");

        // ---- stage out: LDS -> lane-contiguous global f4 stores. Next
        // iteration's ds_write (stage-in) is ordered after these ds_reads by
        // the in-order DS pipe, so no WAR hazard on wlds.
#pragma unroll
        for (int k = 0; k < 5; ++k)
            zout[cur + k * 64 + lane] =
                *reinterpret_cast<const vf4*>(&wlds[(k * 64 + lane) * 4]);

        // hand prefetch to next iteration (full unroll -> SSA rename, no movs)
        if (t + 1 < TILES_PER_WAVE) {
#pragma unroll
            for (int k = 0; k < 5; ++k) r[k] = rn[k];
        }
    }
}

extern "C" void kernel_launch(void* const* d_in, const int* in_sizes, int n_in,
                              void* d_out, int out_size, void* d_ws, size_t ws_size,
                              hipStream_t stream) {
    const float* x   = (const float*)d_in[0];   // [B,5]
    const float* W   = (const float*)d_in[1];   // [5,5]
    const float* bfc = (const float*)d_in[2];   // [5]
    float* out = (float*)d_out;                 // [B,5]

    int total_f4 = in_sizes[0] / 4;             // 5,242,880
    int f4_per_wave = F4_PER_TILE * TILES_PER_WAVE;                    // 1280
    int n_waves  = (total_f4 + f4_per_wave - 1) / f4_per_wave;         // 4096
    int grid     = (n_waves + WAVES_PER_BLOCK - 1) / WAVES_PER_BLOCK;  // 1024

    qpnet_kernel<<<grid, BLOCK, 0, stream>>>(x, W, bfc, out, total_f4);
}

// Round 5
// 151.401 us; speedup vs baseline: 1.0811x; 1.0095x over previous
//
#include <hip/hip_runtime.h>

// qpNet: h = x @ W^T + b ; z = max(-h, -1000). x:[B,5] f32, W:[5,5], b:[5].
// B = 4194304. Memory-bound: 168 MB app traffic, floor ~27 us @ 6.3 TB/s.
//
// R2:  80 B lane stride, one-shot      -> 57 us
// R3:  block LDS transpose + barrier   -> 50 us
// R5:  64 B stride + nontemporal st    -> 82 us (nt defeats L2 write-combine)
// R6:  wave-private LDS transpose      -> ~50 us
// R7:  R6 + reg prefetch               -> 51.4 us, VGPR=28: prefetch sunk.
// R9:  no-LDS copy-shape, 80 B stride  -> 61 us, VGPR=28: same. LDS exonerated.
// R10: R7 + sched_barrier(0) pin       -> 49.6 us, VGPR=32: ambiguous (reg
//      prefetch unverifiable; allocator keeps defeating or minimizing it).
// R11 (this): global_load_lds DOUBLE BUFFER + counted vmcnt (T3/T4 idiom).
//      DMA global->LDS has NO dest VGPRs: nothing to sink, zero liveness
//      cost, so tile t+1's 5 KB is STRUCTURALLY in flight across tile t's
//      whole LDS/compute/store phase. vmcnt never drains to 0 in the loop:
//      issue order per iter is L(t), S(t-1), L(t+1) -> wait vmcnt(10)
//      steady (vmcnt(5) at t=0 and t=3). gload's LDS write (base+lane*16)
//      is exactly R6's conflict-free stage-in layout, so the transposed
//      read is unchanged. LDS 40 KB/block -> 4 blocks/CU, 16 waves/CU.
//      Fork: ~30-38 us => serial chain was the limiter. ~50 us with
//      guaranteed overlap => ~2.5 TB/s service cap is real => ROOFLINE.

#define BLOCK 256
#define WAVES_PER_BLOCK 4          // BLOCK / 64
#define F4_PER_TILE 320            // 64 lanes * 5 f4 = 1280 floats = 256 rows
#define TILES_PER_WAVE 4           // 4096 waves total = 1024 blocks
#define TILE_FLOATS 1280

typedef float vf4 __attribute__((ext_vector_type(4)));

typedef const __attribute__((address_space(1))) void gvoid_t;
typedef __attribute__((address_space(3))) void svoid_t;

__global__ __launch_bounds__(BLOCK) void qpnet_kernel(
    const float* __restrict__ x,
    const float* __restrict__ W,
    const float* __restrict__ bfc,
    float* __restrict__ out,
    int total_f4)
{
    // [wave][dbuf][1280 floats] = 40 KB
    __shared__ __align__(16) float lds[WAVES_PER_BLOCK * 2 * TILE_FLOATS];

    // 5x5 weights + bias (wave-uniform -> scalar-cached).
    float w[5][5];
    float bias[5];
#pragma unroll
    for (int j = 0; j < 5; ++j) {
        bias[j] = bfc[j];
#pragma unroll
        for (int i = 0; i < 5; ++i) w[j][i] = W[j * 5 + i];
    }

    const int wave = threadIdx.x >> 6;
    const int lane = threadIdx.x & 63;
    float* const wbuf = &lds[wave * (2 * TILE_FLOATS)];

    const int wave_id = blockIdx.x * WAVES_PER_BLOCK + wave;
    const int tb = wave_id * (F4_PER_TILE * TILES_PER_WAVE);  // f4 units
    if (tb >= total_f4) return;                               // exact division

    const vf4* __restrict__ xin  = reinterpret_cast<const vf4*>(x);
    vf4* __restrict__       zout = reinterpret_cast<vf4*>(out);

    // ---- prologue: DMA tile 0 into buf0. Per instr k: lanes fill bytes
    // (k*64+lane)*16 of the buffer == R6's stage-in layout exactly.
#pragma unroll
    for (int k = 0; k < 5; ++k) {
        __builtin_amdgcn_global_load_lds(
            (gvoid_t*)(const void*)&xin[tb + k * 64 + lane],
            (svoid_t*)(void*)&wbuf[k * 256], 16, 0, 0);
    }

#pragma unroll
    for (int t = 0; t < TILES_PER_WAVE; ++t) {
        const int cur = tb + t * F4_PER_TILE;
        float* const cbuf = wbuf + (t & 1) * TILE_FLOATS;

        // ---- issue NEXT tile's DMA into the other buffer (fire-and-forget).
        // WAR on that buffer is safe: tile t-2's stage-out ds_reads were
        // drained by lgkmcnt(0) before its stores issued.
        if (t + 1 < TILES_PER_WAVE) {
            float* const nbuf = wbuf + ((t + 1) & 1) * TILE_FLOATS;
            const int nxt = cur + F4_PER_TILE;
#pragma unroll
            for (int k = 0; k < 5; ++k) {
                __builtin_amdgcn_global_load_lds(
                    (gvoid_t*)(const void*)&xin[nxt + k * 64 + lane],
                    (svoid_t*)(void*)&nbuf[k * 256], 16, 0, 0);
            }
        }

        // ---- counted wait: drain L(t) only, leave S(t-1)+L(t+1) in flight.
        // Issue order so far: L(t) [5], S(t-1) [5], L(t+1) [5]; in-order
        // retirement (m135) => vmcnt(10) guarantees L(t) landed in LDS.
        if (t == 0) {
            asm volatile("s_waitcnt vmcnt(5)" ::: "memory");   // only L1 younger
        } else if (t + 1 < TILES_PER_WAVE) {
            asm volatile("s_waitcnt vmcnt(10)" ::: "memory");  // S(t-1)+L(t+1)
        } else {
            asm volatile("s_waitcnt vmcnt(5)" ::: "memory");   // S(t-1) only
        }
        __builtin_amdgcn_sched_barrier(0);

        // ---- transposed read: own 20 consecutive floats = 4 complete rows
        // (word addr lane*20 + 4p: stride-20 f4 groups cover all 32 banks / 8 lanes)
        float v[20];
#pragma unroll
        for (int p = 0; p < 5; ++p)
            *reinterpret_cast<vf4*>(&v[4 * p]) =
                *reinterpret_cast<const vf4*>(&cbuf[lane * 20 + 4 * p]);

        // ---- compute: 4 rows x (5x5 matvec + bias + clamp), in place
#pragma unroll
        for (int k = 0; k < 4; ++k) {
            float t0 = bias[0], t1 = bias[1], t2 = bias[2], t3 = bias[3], t4 = bias[4];
#pragma unroll
            for (int i = 0; i < 5; ++i) {
                const float xv = v[k * 5 + i];
                t0 = fmaf(xv, w[0][i], t0);
                t1 = fmaf(xv, w[1][i], t1);
                t2 = fmaf(xv, w[2][i], t2);
                t3 = fmaf(xv, w[3][i], t3);
                t4 = fmaf(xv, w[4][i], t4);
            }
            v[k * 5 + 0] = fmaxf(-t0, -1000.0f);
            v[k * 5 + 1] = fmaxf(-t1, -1000.0f);
            v[k * 5 + 2] = fmaxf(-t2, -1000.0f);
            v[k * 5 + 3] = fmaxf(-t3, -1000.0f);
            v[k * 5 + 4] = fmaxf(-t4, -1000.0f);
        }

        // ---- transposed write back (in place, same buffer)
#pragma unroll
        for (int p = 0; p < 5; ++p)
            *reinterpret_cast<vf4*>(&cbuf[lane * 20 + 4 * p]) =
                *reinterpret_cast<const vf4*>(&v[4 * p]);
        // cross-lane exchange: drain DS writes before contiguous reads
        asm volatile("s_waitcnt lgkmcnt(0)" ::: "memory");

        // ---- stage out: LDS -> lane-contiguous global f4 stores S(t)
#pragma unroll
        for (int k = 0; k < 5; ++k)
            zout[cur + k * 64 + lane] =
                *reinterpret_cast<const vf4*>(&cbuf[(k * 64 + lane) * 4]);
    }
}

extern "C" void kernel_launch(void* const* d_in, const int* in_sizes, int n_in,
                              void* d_out, int out_size, void* d_ws, size_t ws_size,
                              hipStream_t stream) {
    const float* x   = (const float*)d_in[0];   // [B,5]
    const float* W   = (const float*)d_in[1];   // [5,5]
    const float* bfc = (const float*)d_in[2];   // [5]
    float* out = (float*)d_out;                 // [B,5]

    int total_f4 = in_sizes[0] / 4;             // 5,242,880
    int f4_per_wave = F4_PER_TILE * TILES_PER_WAVE;                    // 1280
    int n_waves  = (total_f4 + f4_per_wave - 1) / f4_per_wave;         // 4096
    int grid     = (n_waves + WAVES_PER_BLOCK - 1) / WAVES_PER_BLOCK;  // 1024

    qpnet_kernel<<<grid, BLOCK, 0, stream>>>(x, W, bfc, out, total_f4);
}